// Round 11
// baseline (405.437 us; speedup 1.0000x reference)
//
#include <hip/hip_runtime.h>

#define NQ    10
#define NPRM  100
#define NBATCH 8192

using F2 = __attribute__((ext_vector_type(2))) float;

__device__ __forceinline__ F2 mk2(float a, float b) { F2 v; v.x = a; v.y = b; return v; }

// ---------------- cross-lane XOR exchange ----------------
// masks 1,2,8: DPP on VALU pipe; 4,16,32: ds_swizzle via __shfl_xor (R7-verified)

template<int LM>
__device__ __forceinline__ float lshf(float v) {
  if constexpr (LM == 1) {
    int r = __builtin_amdgcn_update_dpp(0, __builtin_bit_cast(int, v), 0xB1, 0xF, 0xF, true);
    return __builtin_bit_cast(float, r);
  } else if constexpr (LM == 2) {
    int r = __builtin_amdgcn_update_dpp(0, __builtin_bit_cast(int, v), 0x4E, 0xF, 0xF, true);
    return __builtin_bit_cast(float, r);
  } else if constexpr (LM == 8) {
    int r = __builtin_amdgcn_update_dpp(0, __builtin_bit_cast(int, v), 0x128, 0xF, 0xF, true);
    return __builtin_bit_cast(float, r);
  } else {
    return __shfl_xor(v, LM, 64);
  }
}
template<int LM>
__device__ __forceinline__ F2 lshf2(F2 v) {
  return mk2(lshf<LM>(v.x), lshf<LM>(v.y));
}

// Amplitude index i (10 bits): bits 0..3 = per-lane register index r, bits 4..9 = lane id.
// Wire w corresponds to global bit P = 9 - w (wire 0 = MSB, PennyLane order).

// ================= SCALAR gate set (R7 champion, verified) — bwd circuit =================

template<int P>
__device__ __forceinline__ void g_rx(F2* st, unsigned lane, float c, float s) {
  if constexpr (P < 4) {
    constexpr int m = 1 << P;
#pragma unroll
    for (int r = 0; r < 16; ++r) if (!(r & m)) {
      const int r1 = r | m;
      F2 a0 = st[r], a1 = st[r1];
      st[r]  = mk2(c*a0.x + s*a1.y, c*a0.y - s*a1.x);
      st[r1] = mk2(s*a0.y + c*a1.x, c*a1.y - s*a0.x);
    }
  } else {
    constexpr int lm = 1 << (P - 4);
#pragma unroll
    for (int r = 0; r < 16; ++r) {
      float mx = st[r].x, my = st[r].y;
      float ox = lshf<lm>(mx), oy = lshf<lm>(my);
      st[r] = mk2(c*mx + s*oy, c*my - s*ox);
    }
  }
}

template<int P>
__device__ __forceinline__ void g_u(F2* st, unsigned lane, F2 u00, F2 u01) {
  if constexpr (P < 4) {
    constexpr int m = 1 << P;
#pragma unroll
    for (int r = 0; r < 16; ++r) if (!(r & m)) {
      const int r1 = r | m;
      F2 a0 = st[r], a1 = st[r1];
      st[r]  = mk2(u00.x*a0.x - u00.y*a0.y + u01.x*a1.x - u01.y*a1.y,
                   u00.x*a0.y + u00.y*a0.x + u01.x*a1.y + u01.y*a1.x);
      st[r1] = mk2(-u01.x*a0.x - u01.y*a0.y + u00.x*a1.x + u00.y*a1.y,
                   -u01.x*a0.y + u01.y*a0.x + u00.x*a1.y - u00.y*a1.x);
    }
  } else {
    constexpr int lm = 1 << (P - 4);
    const bool hi = (lane & lm) != 0;
    const float vax = u00.x,               vay = hi ? -u00.y : u00.y;
    const float vbx = hi ? -u01.x : u01.x, vby = u01.y;
#pragma unroll
    for (int r = 0; r < 16; ++r) {
      float mx = st[r].x, my = st[r].y;
      float ox = lshf<lm>(mx), oy = lshf<lm>(my);
      st[r] = mk2(vax*mx - vay*my + vbx*ox - vby*oy,
                  vax*my + vay*mx + vbx*oy + vby*ox);
    }
  }
}

template<int TB, int CB>
__device__ __forceinline__ void g_crx(F2* st, unsigned lane, float c, float s) {
  if constexpr (CB >= 4) {
    const bool act = (lane >> (CB - 4)) & 1u;
    const float ce = act ? c : 1.0f;
    const float se = act ? s : 0.0f;
    g_rx<TB>(st, lane, ce, se);
  } else {
    constexpr int cm = 1 << CB;
    if constexpr (TB < 4) {
#pragma unroll
      for (int r = 0; r < 16; ++r) if ((r & cm) && !(r & (1 << TB))) {
        const int r1 = r | (1 << TB);
        F2 a0 = st[r], a1 = st[r1];
        st[r]  = mk2(c*a0.x + s*a1.y, c*a0.y - s*a1.x);
        st[r1] = mk2(s*a0.y + c*a1.x, c*a1.y - s*a0.x);
      }
    } else {
      constexpr int lm = 1 << (TB - 4);
#pragma unroll
      for (int r = 0; r < 16; ++r) if (r & cm) {
        float mx = st[r].x, my = st[r].y;
        float ox = lshf<lm>(mx), oy = lshf<lm>(my);
        st[r] = mk2(c*mx + s*oy, c*my - s*ox);
      }
    }
  }
}

__device__ __forceinline__ void g_u_w(F2* st, unsigned lane, int w, F2 u00, F2 u01) {
  switch (w) {
    case 0: g_u<9>(st,lane,u00,u01); break;
    case 1: g_u<8>(st,lane,u00,u01); break;
    case 2: g_u<7>(st,lane,u00,u01); break;
    case 3: g_u<6>(st,lane,u00,u01); break;
    case 4: g_u<5>(st,lane,u00,u01); break;
    case 5: g_u<4>(st,lane,u00,u01); break;
    case 6: g_u<3>(st,lane,u00,u01); break;
    case 7: g_u<2>(st,lane,u00,u01); break;
    case 8: g_u<1>(st,lane,u00,u01); break;
    case 9: g_u<0>(st,lane,u00,u01); break;
  }
}

#define CRX_CASE(CW,TW) case (CW)*10+(TW): g_crx<9-(TW), 9-(CW)>(st,lane,c,s); break;
__device__ __forceinline__ void crx_w(F2* st, unsigned lane, int cw, int tw, float c, float s) {
  switch (cw * 10 + tw) {
    CRX_CASE(0,1) CRX_CASE(1,2) CRX_CASE(2,3) CRX_CASE(3,4) CRX_CASE(4,5)
    CRX_CASE(5,6) CRX_CASE(6,7) CRX_CASE(7,8) CRX_CASE(8,9) CRX_CASE(9,0)
    CRX_CASE(1,0) CRX_CASE(2,1) CRX_CASE(3,2) CRX_CASE(4,3) CRX_CASE(5,4)
    CRX_CASE(6,5) CRX_CASE(7,6) CRX_CASE(8,7) CRX_CASE(9,8) CRX_CASE(0,9)
  }
}

// U = RZ(az)*RY(ay)*RX(ax); SU(2): only u00,u01 needed
__device__ __forceinline__ void make_u(float ax, float ay, float az, F2& u00, F2& u01) {
  float ca, sa, cb, sb, cg, sg;
  __sincosf(ax*0.5f, &sa, &ca);
  __sincosf(ay*0.5f, &sb, &cb);
  __sincosf(az*0.5f, &sg, &cg);
  const float m00x =  cb*ca, m00y =  sb*sa;
  const float m01x = -sb*ca, m01y = -cb*sa;
  u00 = mk2(m00x*cg + m00y*sg, m00y*cg - m00x*sg);
  u01 = mk2(m01x*cg + m01y*sg, m01y*cg - m01x*sg);
}

__device__ __forceinline__ void init_state(F2* st, unsigned lane, const float* ang) {
  float cw[NQ], sw[NQ];
#pragma unroll
  for (int w = 0; w < NQ; ++w) __sincosf(ang[w]*0.5f, &sw[w], &cw[w]);
  float L = 1.0f;
#pragma unroll
  for (int q = 0; q < 6; ++q)
    L *= ((lane >> q) & 1u) ? sw[5-q] : cw[5-q];
#pragma unroll
  for (int r = 0; r < 16; ++r) {
    float R = L;
#pragma unroll
    for (int p = 0; p < 4; ++p)
      R *= ((r >> p) & 1) ? sw[9-p] : cw[9-p];
    st[r] = mk2(R, 0.0f);
  }
}

// ================= PAIRED gate set: lo half = fwd circuit, hi half = diag circuit =================
// All operations element-wise on F2 (v2f32 -> packed fp32 with default modifiers; R9-verified).

struct UU { F2 x00, y00, x01, y01; };

template<int P>
__device__ __forceinline__ void g_u2(F2* sR, F2* sI, unsigned lane, UU u) {
  if constexpr (P < 4) {
    constexpr int m = 1 << P;
#pragma unroll
    for (int r = 0; r < 16; ++r) if (!(r & m)) {
      const int r1 = r | m;
      F2 R0 = sR[r], I0 = sI[r], R1 = sR[r1], I1 = sI[r1];
      sR[r]  = u.x00*R0 - u.y00*I0 + u.x01*R1 - u.y01*I1;
      sI[r]  = u.x00*I0 + u.y00*R0 + u.x01*I1 + u.y01*R1;
      sR[r1] = u.x00*R1 + u.y00*I1 - u.x01*R0 - u.y01*I0;
      sI[r1] = u.x00*I1 - u.y00*R1 - u.x01*I0 + u.y01*R0;
    }
  } else {
    constexpr int lm = 1 << (P - 4);
    const bool hi = (lane & lm) != 0;
    const F2 vay = mk2(hi ? -u.y00.x : u.y00.x, hi ? -u.y00.y : u.y00.y);
    const F2 vbx = mk2(hi ? -u.x01.x : u.x01.x, hi ? -u.x01.y : u.x01.y);
#pragma unroll
    for (int r = 0; r < 16; ++r) {
      F2 R = sR[r], I = sI[r];
      F2 oR = lshf2<lm>(R), oI = lshf2<lm>(I);
      sR[r] = u.x00*R - vay*I + vbx*oR - u.y01*oI;
      sI[r] = u.x00*I + vay*R + vbx*oI + u.y01*oR;
    }
  }
}

template<int P>
__device__ __forceinline__ void g_rx2(F2* sR, F2* sI, unsigned lane, F2 C, F2 S) {
  if constexpr (P < 4) {
    constexpr int m = 1 << P;
#pragma unroll
    for (int r = 0; r < 16; ++r) if (!(r & m)) {
      const int r1 = r | m;
      F2 R0 = sR[r], I0 = sI[r], R1 = sR[r1], I1 = sI[r1];
      sR[r]  = C*R0 + S*I1;
      sI[r]  = C*I0 - S*R1;
      sR[r1] = C*R1 + S*I0;
      sI[r1] = C*I1 - S*R0;
    }
  } else {
    constexpr int lm = 1 << (P - 4);
#pragma unroll
    for (int r = 0; r < 16; ++r) {
      F2 R = sR[r], I = sI[r];
      F2 oR = lshf2<lm>(R), oI = lshf2<lm>(I);
      sR[r] = C*R + S*oI;
      sI[r] = C*I - S*oR;
    }
  }
}

template<int TB, int CB>
__device__ __forceinline__ void g_crx2(F2* sR, F2* sI, unsigned lane, F2 C, F2 S) {
  if constexpr (CB >= 4) {
    const bool act = (lane >> (CB - 4)) & 1u;
    const F2 Ce = mk2(act ? C.x : 1.0f, act ? C.y : 1.0f);
    const F2 Se = mk2(act ? S.x : 0.0f, act ? S.y : 0.0f);
    g_rx2<TB>(sR, sI, lane, Ce, Se);
  } else {
    constexpr int cm = 1 << CB;
    if constexpr (TB < 4) {
#pragma unroll
      for (int r = 0; r < 16; ++r) if ((r & cm) && !(r & (1 << TB))) {
        const int r1 = r | (1 << TB);
        F2 R0 = sR[r], I0 = sI[r], R1 = sR[r1], I1 = sI[r1];
        sR[r]  = C*R0 + S*I1;
        sI[r]  = C*I0 - S*R1;
        sR[r1] = C*R1 + S*I0;
        sI[r1] = C*I1 - S*R0;
      }
    } else {
      constexpr int lm = 1 << (TB - 4);
#pragma unroll
      for (int r = 0; r < 16; ++r) if (r & cm) {
        F2 R = sR[r], I = sI[r];
        F2 oR = lshf2<lm>(R), oI = lshf2<lm>(I);
        sR[r] = C*R + S*oI;
        sI[r] = C*I - S*oR;
      }
    }
  }
}

__device__ __forceinline__ void g_u2_w(F2* sR, F2* sI, unsigned lane, int w, UU u) {
  switch (w) {
    case 0: g_u2<9>(sR,sI,lane,u); break;
    case 1: g_u2<8>(sR,sI,lane,u); break;
    case 2: g_u2<7>(sR,sI,lane,u); break;
    case 3: g_u2<6>(sR,sI,lane,u); break;
    case 4: g_u2<5>(sR,sI,lane,u); break;
    case 5: g_u2<4>(sR,sI,lane,u); break;
    case 6: g_u2<3>(sR,sI,lane,u); break;
    case 7: g_u2<2>(sR,sI,lane,u); break;
    case 8: g_u2<1>(sR,sI,lane,u); break;
    case 9: g_u2<0>(sR,sI,lane,u); break;
  }
}

#define CRX2_CASE(CW,TW) case (CW)*10+(TW): g_crx2<9-(TW), 9-(CW)>(sR,sI,lane,C,S); break;
__device__ __forceinline__ void crx2_w(F2* sR, F2* sI, unsigned lane, int cw, int tw, F2 C, F2 S) {
  switch (cw * 10 + tw) {
    CRX2_CASE(0,1) CRX2_CASE(1,2) CRX2_CASE(2,3) CRX2_CASE(3,4) CRX2_CASE(4,5)
    CRX2_CASE(5,6) CRX2_CASE(6,7) CRX2_CASE(7,8) CRX2_CASE(8,9) CRX2_CASE(9,0)
    CRX2_CASE(1,0) CRX2_CASE(2,1) CRX2_CASE(3,2) CRX2_CASE(4,3) CRX2_CASE(5,4)
    CRX2_CASE(6,5) CRX2_CASE(7,6) CRX2_CASE(8,7) CRX2_CASE(9,8) CRX2_CASE(0,9)
  }
}

__device__ __forceinline__ void init_state2(F2* sR, F2* sI, unsigned lane, const float* ang) {
  float cw[NQ], sw[NQ];
#pragma unroll
  for (int w = 0; w < NQ; ++w) __sincosf(ang[w]*0.5f, &sw[w], &cw[w]);
  float L = 1.0f;
#pragma unroll
  for (int q = 0; q < 6; ++q)
    L *= ((lane >> q) & 1u) ? sw[5-q] : cw[5-q];
#pragma unroll
  for (int r = 0; r < 16; ++r) {
    float R = L;
#pragma unroll
    for (int p = 0; p < 4; ++p)
      R *= ((r >> p) & 1) ? sw[9-p] : cw[9-p];
    sR[r] = mk2(R, R);
    sI[r] = mk2(0.0f, 0.0f);
  }
}

// ---------------- measurement (R7 verbatim) ----------------

template<int P>
__device__ __forceinline__ void meas(const F2* st, unsigned lane, float& X, float& Y, float& Z) {
  float cr = 0.f, ci = 0.f, z = 0.f;
  if constexpr (P < 4) {
    constexpr int m = 1 << P;
#pragma unroll
    for (int r = 0; r < 16; ++r) if (!(r & m)) {
      const int r1 = r | m;
      F2 a0 = st[r], a1 = st[r1];
      cr += a0.x*a1.x + a0.y*a1.y;
      ci += a0.x*a1.y - a0.y*a1.x;
      z  += (a0.x*a0.x + a0.y*a0.y) - (a1.x*a1.x + a1.y*a1.y);
    }
    cr *= 2.f; ci *= 2.f;
  } else {
    constexpr int lm = 1 << (P - 4);
    const bool hi = (lane & lm) != 0;
#pragma unroll
    for (int r = 0; r < 16; ++r) {
      float mx = st[r].x, my = st[r].y;
      float ox = lshf<lm>(mx), oy = lshf<lm>(my);
      float a0x = hi ? ox : mx, a0y = hi ? oy : my;
      float a1x = hi ? mx : ox, a1y = hi ? my : oy;
      cr += a0x*a1x + a0y*a1y;
      ci += a0x*a1y - a0y*a1x;
      float p2 = mx*mx + my*my;
      z += hi ? -p2 : p2;
    }
  }
  X = cr; Y = ci; Z = z;
}

__device__ __forceinline__ float wred(float v) {
  v += lshf<1>(v);
  v += lshf<2>(v);
  v += lshf<4>(v);
  v += lshf<8>(v);
  v += lshf<16>(v);
  v += lshf<32>(v);
  return v;
}

// ---------------- kernel: paired {fwd,diag} interleaved gate-by-gate with scalar bwd ----------------
// Two independent dependency chains in one stream: while the paired chain waits on a
// ds_swizzle, the bwd chain's FMAs issue (and vice versa). Per-circuit gate order preserved.
// R10 bug fixed: bwd/paired ring targets are (18-k)%10, not (19-k)%10.

__global__ void __launch_bounds__(256) qsim_kernel(
    const float* __restrict__ angles, const float* __restrict__ fwdP,
    const float* __restrict__ bwdP,   const float* __restrict__ diagP,
    const float* __restrict__ dts,
    const float* __restrict__ ar, const float* __restrict__ ai,
    const float* __restrict__ br, const float* __restrict__ bi,
    const float* __restrict__ gr, const float* __restrict__ gi,
    float* __restrict__ out)
{
  const int tid = blockIdx.x * blockDim.x + threadIdx.x;
  const int b = tid >> 6;
  if (b >= NBATCH) return;
  const unsigned lane = threadIdx.x & 63u;
  const int bu = __builtin_amdgcn_readfirstlane(b);

  const float* ang = angles + bu * NQ;
  const float dt = dts[bu];

  const float arv = ar[0], aiv = ai[0], brv = br[0], biv = bi[0], grv = gr[0], giv = gi[0];
  const float nrm = sqrtf(arv*arv + aiv*aiv + brv*brv + biv*biv + grv*grv + giv*giv + 1e-9f);
  const F2 cA = mk2(arv/nrm, aiv/nrm), cB = mk2(brv/nrm, biv/nrm), cG = mk2(grv/nrm, giv/nrm);

  const float* Pf = fwdP  + bu*NPRM;
  const float* Pd = diagP + bu*NPRM;
  const float* Pb = bwdP  + bu*NPRM;

  F2 sR[16], sI[16];   // paired: lo=fwd, hi=diag
  F2 st[16];           // scalar complex: bwd
  init_state2(sR, sI, lane, ang);
  init_state(st, lane, ang);

  int off = 0;
#pragma unroll
  for (int l = 0; l < 2; ++l) {
    // phase A: single-qubit U gates. paired: wires 0..9 ; bwd: wires 9..0.
#pragma unroll
    for (int k = 0; k < NQ; ++k) {
      {
        F2 u00F, u01F, u00D, u01D;
        make_u(Pf[off]*dt, Pf[off+1]*dt, Pf[off+2]*dt, u00F, u01F);
        make_u(Pd[off],    Pd[off+1],    Pd[off+2],    u00D, u01D);
        UU u;
        u.x00 = mk2(u00F.x, u00D.x); u.y00 = mk2(u00F.y, u00D.y);
        u.x01 = mk2(u01F.x, u01D.x); u.y01 = mk2(u01F.y, u01D.y);
        g_u2_w(sR, sI, lane, k, u);
      }
      {
        F2 u00, u01;
        make_u(Pb[off]*dt, Pb[off+1]*dt, Pb[off+2]*dt, u00, u01);
        g_u_w(st, lane, 9-k, u00, u01);
      }
      off += 3;
    }
    // phase B: paired ring1 CRX(k,(k+1)%10) ; bwd ring CRX(9-k,(18-k)%10): (9,8)...(0,9)
#pragma unroll
    for (int k = 0; k < NQ; ++k) {
      {
        float sF, cF, sD, cD;
        __sincosf(Pf[off]*0.5f, &sF, &cF);
        __sincosf(Pd[off]*0.5f, &sD, &cD);
        crx2_w(sR, sI, lane, k, (k+1)%NQ, mk2(cF,cD), mk2(sF,sD));
      }
      {
        float s, c; __sincosf(Pb[off]*0.5f, &s, &c);
        crx_w(st, lane, 9-k, (18-k)%NQ, c, s);
      }
      ++off;
    }
    // phase C: paired ring2 CRX(9-k,(18-k)%10) ; bwd ring CRX(k,(k+1)%10)
#pragma unroll
    for (int k = 0; k < NQ; ++k) {
      {
        float sF, cF, sD, cD;
        __sincosf(Pf[off]*0.5f, &sF, &cF);
        __sincosf(Pd[off]*0.5f, &sD, &cD);
        crx2_w(sR, sI, lane, 9-k, (18-k)%NQ, mk2(cF,cD), mk2(sF,sD));
      }
      {
        float s, c; __sincosf(Pb[off]*0.5f, &s, &c);
        crx_w(st, lane, k, (k+1)%NQ, c, s);
      }
      ++off;
    }
  }

  // combine: stc = cA*fwd + cG*diag + cB*bwd
  F2 stc[16];
#pragma unroll
  for (int r = 0; r < 16; ++r) {
    stc[r] = mk2(cA.x*sR[r].x - cA.y*sI[r].x + cG.x*sR[r].y - cG.y*sI[r].y
                   + cB.x*st[r].x - cB.y*st[r].y,
                 cA.x*sI[r].x + cA.y*sR[r].x + cG.x*sI[r].y + cG.y*sR[r].y
                   + cB.x*st[r].y + cB.y*st[r].x);
  }

  // global normalize
  float n2 = 0.f;
#pragma unroll
  for (int r = 0; r < 16; ++r) n2 += stc[r].x*stc[r].x + stc[r].y*stc[r].y;
  n2 = wred(n2);
  const float inv = 1.0f / (sqrtf(n2) + 1e-9f);
#pragma unroll
  for (int r = 0; r < 16; ++r) { stc[r] = mk2(stc[r].x*inv, stc[r].y*inv); }

  // measure X/Y/Z per wire
  float* o = out + b * 30;
#pragma unroll
  for (int w = 0; w < NQ; ++w) {
    float X, Y, Z;
    switch (w) {
      case 0: meas<9>(stc, lane, X, Y, Z); break;
      case 1: meas<8>(stc, lane, X, Y, Z); break;
      case 2: meas<7>(stc, lane, X, Y, Z); break;
      case 3: meas<6>(stc, lane, X, Y, Z); break;
      case 4: meas<5>(stc, lane, X, Y, Z); break;
      case 5: meas<4>(stc, lane, X, Y, Z); break;
      case 6: meas<3>(stc, lane, X, Y, Z); break;
      case 7: meas<2>(stc, lane, X, Y, Z); break;
      case 8: meas<1>(stc, lane, X, Y, Z); break;
      default: meas<0>(stc, lane, X, Y, Z); break;
    }
    X = wred(X); Y = wred(Y); Z = wred(Z);
    if (lane == 0) { o[w] = X; o[10 + w] = Y; o[20 + w] = Z; }
  }
}

extern "C" void kernel_launch(void* const* d_in, const int* in_sizes, int n_in,
                              void* d_out, int out_size, void* d_ws, size_t ws_size,
                              hipStream_t stream) {
  const float* angles = (const float*)d_in[0];
  const float* fwdP   = (const float*)d_in[1];
  const float* bwdP   = (const float*)d_in[2];
  const float* diagP  = (const float*)d_in[3];
  const float* dts    = (const float*)d_in[4];
  const float* ar     = (const float*)d_in[5];
  const float* ai     = (const float*)d_in[6];
  const float* br     = (const float*)d_in[7];
  const float* bi     = (const float*)d_in[8];
  const float* gr     = (const float*)d_in[9];
  const float* gi     = (const float*)d_in[10];
  float* out = (float*)d_out;

  const int threads = 256;                       // 4 waves/block, 1 batch elem/wave
  const int blocks  = NBATCH / (threads / 64);   // 2048
  qsim_kernel<<<blocks, threads, 0, stream>>>(
      angles, fwdP, bwdP, diagP, dts, ar, ai, br, bi, gr, gi, out);
}

// Round 12
// 266.334 us; speedup vs baseline: 1.5223x; 1.5223x over previous
//
#include <hip/hip_runtime.h>

#define NQ    10
#define NPRM  100
#define NBATCH 8192

using F2 = __attribute__((ext_vector_type(2))) float;

__device__ __forceinline__ F2 mk2(float a, float b) { F2 v; v.x = a; v.y = b; return v; }

// ---------------- cross-lane XOR exchange ----------------
// masks 1,2,8: DPP on VALU pipe; 4,16,32: ds_swizzle via __shfl_xor (R7-verified)

template<int LM>
__device__ __forceinline__ float lshf(float v) {
  if constexpr (LM == 1) {
    int r = __builtin_amdgcn_update_dpp(0, __builtin_bit_cast(int, v), 0xB1, 0xF, 0xF, true);
    return __builtin_bit_cast(float, r);
  } else if constexpr (LM == 2) {
    int r = __builtin_amdgcn_update_dpp(0, __builtin_bit_cast(int, v), 0x4E, 0xF, 0xF, true);
    return __builtin_bit_cast(float, r);
  } else if constexpr (LM == 8) {
    int r = __builtin_amdgcn_update_dpp(0, __builtin_bit_cast(int, v), 0x128, 0xF, 0xF, true);
    return __builtin_bit_cast(float, r);
  } else {
    return __shfl_xor(v, LM, 64);
  }
}
template<int LM>
__device__ __forceinline__ F2 lshf2(F2 v) {
  return mk2(lshf<LM>(v.x), lshf<LM>(v.y));
}

// Amplitude index i (10 bits): bits 0..3 = per-lane register index r, bits 4..9 = lane id.
// Wire w corresponds to global bit P = 9 - w (wire 0 = MSB, PennyLane order).

// ================= SCALAR gate set (R7 champion, verified) — bwd circuit =================

template<int P>
__device__ __forceinline__ void g_rx(F2* st, unsigned lane, float c, float s) {
  if constexpr (P < 4) {
    constexpr int m = 1 << P;
#pragma unroll
    for (int r = 0; r < 16; ++r) if (!(r & m)) {
      const int r1 = r | m;
      F2 a0 = st[r], a1 = st[r1];
      st[r]  = mk2(c*a0.x + s*a1.y, c*a0.y - s*a1.x);
      st[r1] = mk2(s*a0.y + c*a1.x, c*a1.y - s*a0.x);
    }
  } else {
    constexpr int lm = 1 << (P - 4);
#pragma unroll
    for (int r = 0; r < 16; ++r) {
      float mx = st[r].x, my = st[r].y;
      float ox = lshf<lm>(mx), oy = lshf<lm>(my);
      st[r] = mk2(c*mx + s*oy, c*my - s*ox);
    }
  }
}

template<int P>
__device__ __forceinline__ void g_u(F2* st, unsigned lane, F2 u00, F2 u01) {
  if constexpr (P < 4) {
    constexpr int m = 1 << P;
#pragma unroll
    for (int r = 0; r < 16; ++r) if (!(r & m)) {
      const int r1 = r | m;
      F2 a0 = st[r], a1 = st[r1];
      st[r]  = mk2(u00.x*a0.x - u00.y*a0.y + u01.x*a1.x - u01.y*a1.y,
                   u00.x*a0.y + u00.y*a0.x + u01.x*a1.y + u01.y*a1.x);
      st[r1] = mk2(-u01.x*a0.x - u01.y*a0.y + u00.x*a1.x + u00.y*a1.y,
                   -u01.x*a0.y + u01.y*a0.x + u00.x*a1.y - u00.y*a1.x);
    }
  } else {
    constexpr int lm = 1 << (P - 4);
    const bool hi = (lane & lm) != 0;
    const float vax = u00.x,               vay = hi ? -u00.y : u00.y;
    const float vbx = hi ? -u01.x : u01.x, vby = u01.y;
#pragma unroll
    for (int r = 0; r < 16; ++r) {
      float mx = st[r].x, my = st[r].y;
      float ox = lshf<lm>(mx), oy = lshf<lm>(my);
      st[r] = mk2(vax*mx - vay*my + vbx*ox - vby*oy,
                  vax*my + vay*mx + vbx*oy + vby*ox);
    }
  }
}

template<int TB, int CB>
__device__ __forceinline__ void g_crx(F2* st, unsigned lane, float c, float s) {
  if constexpr (CB >= 4) {
    const bool act = (lane >> (CB - 4)) & 1u;
    const float ce = act ? c : 1.0f;
    const float se = act ? s : 0.0f;
    g_rx<TB>(st, lane, ce, se);
  } else {
    constexpr int cm = 1 << CB;
    if constexpr (TB < 4) {
#pragma unroll
      for (int r = 0; r < 16; ++r) if ((r & cm) && !(r & (1 << TB))) {
        const int r1 = r | (1 << TB);
        F2 a0 = st[r], a1 = st[r1];
        st[r]  = mk2(c*a0.x + s*a1.y, c*a0.y - s*a1.x);
        st[r1] = mk2(s*a0.y + c*a1.x, c*a1.y - s*a0.x);
      }
    } else {
      constexpr int lm = 1 << (TB - 4);
#pragma unroll
      for (int r = 0; r < 16; ++r) if (r & cm) {
        float mx = st[r].x, my = st[r].y;
        float ox = lshf<lm>(mx), oy = lshf<lm>(my);
        st[r] = mk2(c*mx + s*oy, c*my - s*ox);
      }
    }
  }
}

__device__ __forceinline__ void g_u_w(F2* st, unsigned lane, int w, F2 u00, F2 u01) {
  switch (w) {
    case 0: g_u<9>(st,lane,u00,u01); break;
    case 1: g_u<8>(st,lane,u00,u01); break;
    case 2: g_u<7>(st,lane,u00,u01); break;
    case 3: g_u<6>(st,lane,u00,u01); break;
    case 4: g_u<5>(st,lane,u00,u01); break;
    case 5: g_u<4>(st,lane,u00,u01); break;
    case 6: g_u<3>(st,lane,u00,u01); break;
    case 7: g_u<2>(st,lane,u00,u01); break;
    case 8: g_u<1>(st,lane,u00,u01); break;
    case 9: g_u<0>(st,lane,u00,u01); break;
  }
}

#define CRX_CASE(CW,TW) case (CW)*10+(TW): g_crx<9-(TW), 9-(CW)>(st,lane,c,s); break;
__device__ __forceinline__ void crx_w(F2* st, unsigned lane, int cw, int tw, float c, float s) {
  switch (cw * 10 + tw) {
    CRX_CASE(0,1) CRX_CASE(1,2) CRX_CASE(2,3) CRX_CASE(3,4) CRX_CASE(4,5)
    CRX_CASE(5,6) CRX_CASE(6,7) CRX_CASE(7,8) CRX_CASE(8,9) CRX_CASE(9,0)
    CRX_CASE(1,0) CRX_CASE(2,1) CRX_CASE(3,2) CRX_CASE(4,3) CRX_CASE(5,4)
    CRX_CASE(6,5) CRX_CASE(7,6) CRX_CASE(8,7) CRX_CASE(9,8) CRX_CASE(0,9)
  }
}

// U = RZ(az)*RY(ay)*RX(ax); SU(2): only u00,u01 needed
__device__ __forceinline__ void make_u(float ax, float ay, float az, F2& u00, F2& u01) {
  float ca, sa, cb, sb, cg, sg;
  __sincosf(ax*0.5f, &sa, &ca);
  __sincosf(ay*0.5f, &sb, &cb);
  __sincosf(az*0.5f, &sg, &cg);
  const float m00x =  cb*ca, m00y =  sb*sa;
  const float m01x = -sb*ca, m01y = -cb*sa;
  u00 = mk2(m00x*cg + m00y*sg, m00y*cg - m00x*sg);
  u01 = mk2(m01x*cg + m01y*sg, m01y*cg - m01x*sg);
}

__device__ __forceinline__ void layer_bwd(F2* st, unsigned lane, const float* P, float dt, int& off) {
#pragma unroll
  for (int i = NQ-1; i >= 0; --i) {
    F2 u00, u01;
    make_u(P[off]*dt, P[off+1]*dt, P[off+2]*dt, u00, u01);
    g_u_w(st, lane, i, u00, u01);
    off += 3;
  }
#pragma unroll
  for (int i = NQ-1; i >= 0; --i) {
    float s, c; __sincosf(P[off]*0.5f, &s, &c);
    crx_w(st, lane, i, (i+NQ-1)%NQ, c, s); ++off;
  }
#pragma unroll
  for (int i = 0; i < NQ; ++i) {
    float s, c; __sincosf(P[off]*0.5f, &s, &c);
    crx_w(st, lane, i, (i+1)%NQ, c, s); ++off;
  }
}

__device__ __forceinline__ void init_state(F2* st, unsigned lane, const float* ang) {
  float cw[NQ], sw[NQ];
#pragma unroll
  for (int w = 0; w < NQ; ++w) __sincosf(ang[w]*0.5f, &sw[w], &cw[w]);
  float L = 1.0f;
#pragma unroll
  for (int q = 0; q < 6; ++q)
    L *= ((lane >> q) & 1u) ? sw[5-q] : cw[5-q];
#pragma unroll
  for (int r = 0; r < 16; ++r) {
    float R = L;
#pragma unroll
    for (int p = 0; p < 4; ++p)
      R *= ((r >> p) & 1) ? sw[9-p] : cw[9-p];
    st[r] = mk2(R, 0.0f);
  }
}

// ================= PAIRED gate set: lo half = fwd circuit, hi half = diag circuit =================
// All operations element-wise on F2 (v2f32 -> packed fp32 with default modifiers; R9-verified).

struct UU { F2 x00, y00, x01, y01; };

template<int P>
__device__ __forceinline__ void g_u2(F2* sR, F2* sI, unsigned lane, UU u) {
  if constexpr (P < 4) {
    constexpr int m = 1 << P;
#pragma unroll
    for (int r = 0; r < 16; ++r) if (!(r & m)) {
      const int r1 = r | m;
      F2 R0 = sR[r], I0 = sI[r], R1 = sR[r1], I1 = sI[r1];
      sR[r]  = u.x00*R0 - u.y00*I0 + u.x01*R1 - u.y01*I1;
      sI[r]  = u.x00*I0 + u.y00*R0 + u.x01*I1 + u.y01*R1;
      sR[r1] = u.x00*R1 + u.y00*I1 - u.x01*R0 - u.y01*I0;
      sI[r1] = u.x00*I1 - u.y00*R1 - u.x01*I0 + u.y01*R0;
    }
  } else {
    constexpr int lm = 1 << (P - 4);
    const bool hi = (lane & lm) != 0;
    const F2 vay = mk2(hi ? -u.y00.x : u.y00.x, hi ? -u.y00.y : u.y00.y);
    const F2 vbx = mk2(hi ? -u.x01.x : u.x01.x, hi ? -u.x01.y : u.x01.y);
#pragma unroll
    for (int r = 0; r < 16; ++r) {
      F2 R = sR[r], I = sI[r];
      F2 oR = lshf2<lm>(R), oI = lshf2<lm>(I);
      sR[r] = u.x00*R - vay*I + vbx*oR - u.y01*oI;
      sI[r] = u.x00*I + vay*R + vbx*oI + u.y01*oR;
    }
  }
}

template<int P>
__device__ __forceinline__ void g_rx2(F2* sR, F2* sI, unsigned lane, F2 C, F2 S) {
  if constexpr (P < 4) {
    constexpr int m = 1 << P;
#pragma unroll
    for (int r = 0; r < 16; ++r) if (!(r & m)) {
      const int r1 = r | m;
      F2 R0 = sR[r], I0 = sI[r], R1 = sR[r1], I1 = sI[r1];
      sR[r]  = C*R0 + S*I1;
      sI[r]  = C*I0 - S*R1;
      sR[r1] = C*R1 + S*I0;
      sI[r1] = C*I1 - S*R0;
    }
  } else {
    constexpr int lm = 1 << (P - 4);
#pragma unroll
    for (int r = 0; r < 16; ++r) {
      F2 R = sR[r], I = sI[r];
      F2 oR = lshf2<lm>(R), oI = lshf2<lm>(I);
      sR[r] = C*R + S*oI;
      sI[r] = C*I - S*oR;
    }
  }
}

template<int TB, int CB>
__device__ __forceinline__ void g_crx2(F2* sR, F2* sI, unsigned lane, F2 C, F2 S) {
  if constexpr (CB >= 4) {
    const bool act = (lane >> (CB - 4)) & 1u;
    const F2 Ce = mk2(act ? C.x : 1.0f, act ? C.y : 1.0f);
    const F2 Se = mk2(act ? S.x : 0.0f, act ? S.y : 0.0f);
    g_rx2<TB>(sR, sI, lane, Ce, Se);
  } else {
    constexpr int cm = 1 << CB;
    if constexpr (TB < 4) {
#pragma unroll
      for (int r = 0; r < 16; ++r) if ((r & cm) && !(r & (1 << TB))) {
        const int r1 = r | (1 << TB);
        F2 R0 = sR[r], I0 = sI[r], R1 = sR[r1], I1 = sI[r1];
        sR[r]  = C*R0 + S*I1;
        sI[r]  = C*I0 - S*R1;
        sR[r1] = C*R1 + S*I0;
        sI[r1] = C*I1 - S*R0;
      }
    } else {
      constexpr int lm = 1 << (TB - 4);
#pragma unroll
      for (int r = 0; r < 16; ++r) if (r & cm) {
        F2 R = sR[r], I = sI[r];
        F2 oR = lshf2<lm>(R), oI = lshf2<lm>(I);
        sR[r] = C*R + S*oI;
        sI[r] = C*I - S*oR;
      }
    }
  }
}

__device__ __forceinline__ void g_u2_w(F2* sR, F2* sI, unsigned lane, int w, UU u) {
  switch (w) {
    case 0: g_u2<9>(sR,sI,lane,u); break;
    case 1: g_u2<8>(sR,sI,lane,u); break;
    case 2: g_u2<7>(sR,sI,lane,u); break;
    case 3: g_u2<6>(sR,sI,lane,u); break;
    case 4: g_u2<5>(sR,sI,lane,u); break;
    case 5: g_u2<4>(sR,sI,lane,u); break;
    case 6: g_u2<3>(sR,sI,lane,u); break;
    case 7: g_u2<2>(sR,sI,lane,u); break;
    case 8: g_u2<1>(sR,sI,lane,u); break;
    case 9: g_u2<0>(sR,sI,lane,u); break;
  }
}

#define CRX2_CASE(CW,TW) case (CW)*10+(TW): g_crx2<9-(TW), 9-(CW)>(sR,sI,lane,C,S); break;
__device__ __forceinline__ void crx2_w(F2* sR, F2* sI, unsigned lane, int cw, int tw, F2 C, F2 S) {
  switch (cw * 10 + tw) {
    CRX2_CASE(0,1) CRX2_CASE(1,2) CRX2_CASE(2,3) CRX2_CASE(3,4) CRX2_CASE(4,5)
    CRX2_CASE(5,6) CRX2_CASE(6,7) CRX2_CASE(7,8) CRX2_CASE(8,9) CRX2_CASE(9,0)
    CRX2_CASE(1,0) CRX2_CASE(2,1) CRX2_CASE(3,2) CRX2_CASE(4,3) CRX2_CASE(5,4)
    CRX2_CASE(6,5) CRX2_CASE(7,6) CRX2_CASE(8,7) CRX2_CASE(9,8) CRX2_CASE(0,9)
  }
}

// paired forward layer: lo = fwd (params*dt), hi = diag (params*1)
__device__ __forceinline__ void layer_fwd2(F2* sR, F2* sI, unsigned lane,
                                           const float* Pf, const float* Pd, float dt, int& off) {
#pragma unroll
  for (int i = 0; i < NQ; ++i) {
    F2 u00F, u01F, u00D, u01D;
    make_u(Pf[off]*dt, Pf[off+1]*dt, Pf[off+2]*dt, u00F, u01F);
    make_u(Pd[off],    Pd[off+1],    Pd[off+2],    u00D, u01D);
    UU u;
    u.x00 = mk2(u00F.x, u00D.x); u.y00 = mk2(u00F.y, u00D.y);
    u.x01 = mk2(u01F.x, u01D.x); u.y01 = mk2(u01F.y, u01D.y);
    g_u2_w(sR, sI, lane, i, u);
    off += 3;
  }
#pragma unroll
  for (int i = 0; i < NQ; ++i) {
    float sF, cF, sD, cD;
    __sincosf(Pf[off]*0.5f, &sF, &cF);
    __sincosf(Pd[off]*0.5f, &sD, &cD);
    crx2_w(sR, sI, lane, i, (i+1)%NQ, mk2(cF,cD), mk2(sF,sD)); ++off;
  }
#pragma unroll
  for (int i = NQ-1; i >= 0; --i) {
    float sF, cF, sD, cD;
    __sincosf(Pf[off]*0.5f, &sF, &cF);
    __sincosf(Pd[off]*0.5f, &sD, &cD);
    crx2_w(sR, sI, lane, i, (i+NQ-1)%NQ, mk2(cF,cD), mk2(sF,sD)); ++off;
  }
}

__device__ __forceinline__ void init_state2(F2* sR, F2* sI, unsigned lane, const float* ang) {
  float cw[NQ], sw[NQ];
#pragma unroll
  for (int w = 0; w < NQ; ++w) __sincosf(ang[w]*0.5f, &sw[w], &cw[w]);
  float L = 1.0f;
#pragma unroll
  for (int q = 0; q < 6; ++q)
    L *= ((lane >> q) & 1u) ? sw[5-q] : cw[5-q];
#pragma unroll
  for (int r = 0; r < 16; ++r) {
    float R = L;
#pragma unroll
    for (int p = 0; p < 4; ++p)
      R *= ((r >> p) & 1) ? sw[9-p] : cw[9-p];
    sR[r] = mk2(R, R);
    sI[r] = mk2(0.0f, 0.0f);
  }
}

// ---------------- measurement (R7 verbatim) ----------------

template<int P>
__device__ __forceinline__ void meas(const F2* st, unsigned lane, float& X, float& Y, float& Z) {
  float cr = 0.f, ci = 0.f, z = 0.f;
  if constexpr (P < 4) {
    constexpr int m = 1 << P;
#pragma unroll
    for (int r = 0; r < 16; ++r) if (!(r & m)) {
      const int r1 = r | m;
      F2 a0 = st[r], a1 = st[r1];
      cr += a0.x*a1.x + a0.y*a1.y;
      ci += a0.x*a1.y - a0.y*a1.x;
      z  += (a0.x*a0.x + a0.y*a0.y) - (a1.x*a1.x + a1.y*a1.y);
    }
    cr *= 2.f; ci *= 2.f;
  } else {
    constexpr int lm = 1 << (P - 4);
    const bool hi = (lane & lm) != 0;
#pragma unroll
    for (int r = 0; r < 16; ++r) {
      float mx = st[r].x, my = st[r].y;
      float ox = lshf<lm>(mx), oy = lshf<lm>(my);
      float a0x = hi ? ox : mx, a0y = hi ? oy : my;
      float a1x = hi ? mx : ox, a1y = hi ? my : oy;
      cr += a0x*a1x + a0y*a1y;
      ci += a0x*a1y - a0y*a1x;
      float p2 = mx*mx + my*my;
      z += hi ? -p2 : p2;
    }
  }
  X = cr; Y = ci; Z = z;
}

__device__ __forceinline__ float wred(float v) {
  v += lshf<1>(v);
  v += lshf<2>(v);
  v += lshf<4>(v);
  v += lshf<8>(v);
  v += lshf<16>(v);
  v += lshf<32>(v);
  return v;
}

// ---------------- kernel: R9 structure + min-waves=3 (VGPR cap 85 -> 3 waves/SIMD) ----------------
// Model (R7/R9/R11 calibrated): waves/SIMD = floor(256/VGPR); busy 96%@3, 70%@2, 53%@1.
// R9's peak live set is ~84 regs (paired: sR+sI=64+temps; bwd: stc+st=64+temps); VGPR=112
// was compiler slack. Cap at 85 must not spill: tripwire = WRITE_SIZE blowup.

__global__ void __launch_bounds__(256, 3) qsim_kernel(
    const float* __restrict__ angles, const float* __restrict__ fwdP,
    const float* __restrict__ bwdP,   const float* __restrict__ diagP,
    const float* __restrict__ dts,
    const float* __restrict__ ar, const float* __restrict__ ai,
    const float* __restrict__ br, const float* __restrict__ bi,
    const float* __restrict__ gr, const float* __restrict__ gi,
    float* __restrict__ out)
{
  const int tid = blockIdx.x * blockDim.x + threadIdx.x;
  const int b = tid >> 6;
  if (b >= NBATCH) return;
  const unsigned lane = threadIdx.x & 63u;
  const int bu = __builtin_amdgcn_readfirstlane(b);

  const float* ang = angles + bu * NQ;
  const float dt = dts[bu];

  const float arv = ar[0], aiv = ai[0], brv = br[0], biv = bi[0], grv = gr[0], giv = gi[0];
  const float nrm = sqrtf(arv*arv + aiv*aiv + brv*brv + biv*biv + grv*grv + giv*giv + 1e-9f);
  const F2 cA = mk2(arv/nrm, aiv/nrm), cB = mk2(brv/nrm, biv/nrm), cG = mk2(grv/nrm, giv/nrm);

  F2 stc[16];

  // phase 1: paired {fwd (lo), diag (hi)} simulation — sR/sI die at scope end
  {
    F2 sR[16], sI[16];
    init_state2(sR, sI, lane, ang);
    int off = 0;
    const float* Pf = fwdP  + bu*NPRM;
    const float* Pd = diagP + bu*NPRM;
#pragma unroll
    for (int l = 0; l < 2; ++l) layer_fwd2(sR, sI, lane, Pf, Pd, dt, off);
#pragma unroll
    for (int r = 0; r < 16; ++r) {
      stc[r] = mk2(cA.x*sR[r].x - cA.y*sI[r].x + cG.x*sR[r].y - cG.y*sI[r].y,
                   cA.x*sI[r].x + cA.y*sR[r].x + cG.x*sI[r].y + cG.y*sR[r].y);
    }
  }

  // phase 2: bwd circuit, scalar (R7 path)
  {
    F2 st[16];
    init_state(st, lane, ang);
    int off = 0;
    const float* P = bwdP + bu*NPRM;
#pragma unroll
    for (int l = 0; l < 2; ++l) layer_bwd(st, lane, P, dt, off);
#pragma unroll
    for (int r = 0; r < 16; ++r) {
      stc[r] = mk2(stc[r].x + cB.x*st[r].x - cB.y*st[r].y,
                   stc[r].y + cB.x*st[r].y + cB.y*st[r].x);
    }
  }

  // global normalize
  float n2 = 0.f;
#pragma unroll
  for (int r = 0; r < 16; ++r) n2 += stc[r].x*stc[r].x + stc[r].y*stc[r].y;
  n2 = wred(n2);
  const float inv = 1.0f / (sqrtf(n2) + 1e-9f);
#pragma unroll
  for (int r = 0; r < 16; ++r) { stc[r] = mk2(stc[r].x*inv, stc[r].y*inv); }

  // measure X/Y/Z per wire
  float* o = out + b * 30;
#pragma unroll
  for (int w = 0; w < NQ; ++w) {
    float X, Y, Z;
    switch (w) {
      case 0: meas<9>(stc, lane, X, Y, Z); break;
      case 1: meas<8>(stc, lane, X, Y, Z); break;
      case 2: meas<7>(stc, lane, X, Y, Z); break;
      case 3: meas<6>(stc, lane, X, Y, Z); break;
      case 4: meas<5>(stc, lane, X, Y, Z); break;
      case 5: meas<4>(stc, lane, X, Y, Z); break;
      case 6: meas<3>(stc, lane, X, Y, Z); break;
      case 7: meas<2>(stc, lane, X, Y, Z); break;
      case 8: meas<1>(stc, lane, X, Y, Z); break;
      default: meas<0>(stc, lane, X, Y, Z); break;
    }
    X = wred(X); Y = wred(Y); Z = wred(Z);
    if (lane == 0) { o[w] = X; o[10 + w] = Y; o[20 + w] = Z; }
  }
}

extern "C" void kernel_launch(void* const* d_in, const int* in_sizes, int n_in,
                              void* d_out, int out_size, void* d_ws, size_t ws_size,
                              hipStream_t stream) {
  const float* angles = (const float*)d_in[0];
  const float* fwdP   = (const float*)d_in[1];
  const float* bwdP   = (const float*)d_in[2];
  const float* diagP  = (const float*)d_in[3];
  const float* dts    = (const float*)d_in[4];
  const float* ar     = (const float*)d_in[5];
  const float* ai     = (const float*)d_in[6];
  const float* br     = (const float*)d_in[7];
  const float* bi     = (const float*)d_in[8];
  const float* gr     = (const float*)d_in[9];
  const float* gi     = (const float*)d_in[10];
  float* out = (float*)d_out;

  const int threads = 256;                       // 4 waves/block, 1 batch elem/wave
  const int blocks  = NBATCH / (threads / 64);   // 2048
  qsim_kernel<<<blocks, threads, 0, stream>>>(
      angles, fwdP, bwdP, diagP, dts, ar, ai, br, bi, gr, gi, out);
}